// Round 1
// baseline (115.336 us; speedup 1.0000x reference)
//
#include <hip/hip_runtime.h>
#include <cstdint>

typedef __bf16 v8bf __attribute__((ext_vector_type(8)));
typedef float f32x4 __attribute__((ext_vector_type(4)));

#define BN_EPS 1e-5f

__device__ __forceinline__ float b2f(uint32_t u) {        // low 16 bits = bf16
    union { uint32_t i; float f; } v; v.i = u << 16; return v.f;
}
__device__ __forceinline__ uint16_t f2b(float f) {        // RNE fp32 -> bf16
    uint32_t u = __builtin_bit_cast(uint32_t, f);
    u += 0x7fffu + ((u >> 16) & 1u);
    return (uint16_t)(u >> 16);
}

// ---------------------------------------------------------------------------
// prep: wT_all[512][128] bf16 = [w_value^T ; w_off^T ; w_out^T], + BN consts
// ---------------------------------------------------------------------------
__global__ void prep_kernel(const float* __restrict__ wv, const float* __restrict__ wo,
                            const float* __restrict__ wout,
                            const float* __restrict__ gamma, const float* __restrict__ beta,
                            const float* __restrict__ mean, const float* __restrict__ var,
                            uint16_t* __restrict__ wT, float* __restrict__ bnc) {
    int idx = blockIdx.x * 256 + threadIdx.x;
    if (idx < 512 * 128) {
        int r = idx >> 7, ci = idx & 127;
        float v;
        if (r < 128)      v = wv[ci * 128 + r];
        else if (r < 384) v = wo[ci * 256 + (r - 128)];
        else              v = wout[ci * 128 + (r - 384)];
        wT[idx] = f2b(v);
    }
    if (idx < 128) {
        float inv = gamma[idx] * rsqrtf(var[idx] + BN_EPS);
        bnc[idx] = inv;
        bnc[128 + idx] = beta[idx] - mean[idx] * inv;
    }
}

// ---------------------------------------------------------------------------
// transpose: x (N,C,H,W) fp32 -> xf[(n*P+p)][c] bf16    (NHWC rows)
// ---------------------------------------------------------------------------
__global__ void transpose_kernel(const float* __restrict__ x, uint16_t* __restrict__ xf) {
    __shared__ float lds[64 * 65];
    int bid = blockIdx.x;
    int cb = bid & 1, pb = (bid >> 1) & 63, n = bid >> 7;
    int c0 = cb * 64, p0 = pb * 64;
    int l = threadIdx.x & 63, q = threadIdx.x >> 6;
    const float* xp = x + ((size_t)(n * 128 + c0)) * 4096 + p0;
#pragma unroll
    for (int i = 0; i < 16; i++) {
        int c = i * 4 + q;
        lds[l * 65 + c] = xp[(size_t)c * 4096 + l];
    }
    __syncthreads();
#pragma unroll
    for (int i = 0; i < 16; i++) {
        int pr = i * 4 + q;
        xf[((size_t)(n * 4096 + p0 + pr)) * 128 + c0 + l] = f2b(lds[pr * 65 + l]);
    }
}

// ---------------------------------------------------------------------------
// gemm1: D[m=out-col][n=pixel] = wT_all[0:384] x xf^T, K=128 fully in LDS.
// cols 0..127 -> val (n,g,p,cg) bf16 ; cols 128..383 -> om (n,p,256) bf16
// ---------------------------------------------------------------------------
__launch_bounds__(256)
__global__ void gemm1_kernel(const uint16_t* __restrict__ xf, const uint16_t* __restrict__ wT,
                             const float* __restrict__ b_value, const float* __restrict__ b_off,
                             uint16_t* __restrict__ valb, uint16_t* __restrict__ omb) {
    __shared__ __align__(16) uint16_t ldsX[128 * 136];
    __shared__ __align__(16) uint16_t ldsW[64 * 136];
    int ct = blockIdx.x;            // 0..5  -> 64 output cols
    int pt = blockIdx.y;            // 0..127 -> 128 pixels
    int p0 = pt * 128, cbase = ct * 64;
    int tid = threadIdx.x;
    int col16 = tid & 15, rowq = tid >> 4;

    const uint4* xg = (const uint4*)xf;
    uint4* lx = (uint4*)ldsX;
#pragma unroll
    for (int i = 0; i < 8; i++) {
        int row = i * 16 + rowq;
        lx[row * 17 + col16] = xg[(size_t)(p0 + row) * 16 + col16];
    }
    const uint4* wg = (const uint4*)wT;
    uint4* lw = (uint4*)ldsW;
#pragma unroll
    for (int i = 0; i < 4; i++) {
        int row = i * 16 + rowq;
        lw[row * 17 + col16] = wg[(size_t)(cbase + row) * 16 + col16];
    }
    __syncthreads();

    int wv = tid >> 6, lane = tid & 63;
    int ln = lane & 15, quad = lane >> 4;
    int cW = cbase + wv * 16 + quad * 4;          // this lane's 4 output cols
    f32x4 binit;
    if (cW < 128) binit = f32x4{b_value[cW], b_value[cW + 1], b_value[cW + 2], b_value[cW + 3]};
    else          binit = f32x4{b_off[cW - 128], b_off[cW - 127], b_off[cW - 126], b_off[cW - 125]};
    f32x4 acc[8];
#pragma unroll
    for (int t = 0; t < 8; t++) acc[t] = binit;

#pragma unroll
    for (int kk = 0; kk < 4; kk++) {
        v8bf a = *(const v8bf*)&ldsW[(wv * 16 + ln) * 136 + kk * 32 + quad * 8];
#pragma unroll
        for (int t = 0; t < 8; t++) {
            v8bf b = *(const v8bf*)&ldsX[(t * 16 + ln) * 136 + kk * 32 + quad * 8];
            acc[t] = __builtin_amdgcn_mfma_f32_16x16x32_bf16(a, b, acc[t], 0, 0, 0);
        }
    }

    int nimg = p0 >> 12, pin0 = p0 & 4095;
    if (cW < 128) {
        int g = cW >> 4, cg = cW & 15;            // cg == quad*4
#pragma unroll
        for (int t = 0; t < 8; t++) {
            int p = pin0 + t * 16 + ln;
            uint32_t u0 = (uint32_t)f2b(acc[t][0]) | ((uint32_t)f2b(acc[t][1]) << 16);
            uint32_t u1 = (uint32_t)f2b(acc[t][2]) | ((uint32_t)f2b(acc[t][3]) << 16);
            *(uint2*)&valb[(((size_t)(nimg * 8 + g) * 4096 + p) << 4) + cg] = make_uint2(u0, u1);
        }
    } else {
        int j0 = cW - 128;
#pragma unroll
        for (int t = 0; t < 8; t++) {
            int p = pin0 + t * 16 + ln;
            uint32_t u0 = (uint32_t)f2b(acc[t][0]) | ((uint32_t)f2b(acc[t][1]) << 16);
            uint32_t u1 = (uint32_t)f2b(acc[t][2]) | ((uint32_t)f2b(acc[t][3]) << 16);
            *(uint2*)&omb[((size_t)(nimg * 4096 + p) << 8) + j0] = make_uint2(u0, u1);
        }
    }
}

// ---------------------------------------------------------------------------
// gather: thread = (n, p, g). 9 taps x 4 corners x 16 ch bilinear, mask folded.
// writes acc (n*P+p, c=g*16+cg) bf16 == GEMM3 A layout
// ---------------------------------------------------------------------------
__launch_bounds__(256)
__global__ void gather_kernel(const uint16_t* __restrict__ omb, const uint16_t* __restrict__ valb,
                              uint16_t* __restrict__ accb) {
    int tid = threadIdx.x, bid = blockIdx.x;      // 512 blocks
    int n = bid >> 7, pch = bid & 127;
    int g = tid & 7, pl = tid >> 3;
    int p = pch * 32 + pl;
    int py = p >> 6, px = p & 63;

    const uint16_t* op = omb + (((size_t)(n * 4096 + p)) << 8) + g * 32;
    uint4 q0 = *(const uint4*)(op);
    uint4 q1 = *(const uint4*)(op + 8);
    uint4 q2 = *(const uint4*)(op + 16);
    uint2 q3 = *(const uint2*)(op + 24);
    uint32_t w[14] = {q0.x, q0.y, q0.z, q0.w, q1.x, q1.y, q1.z, q1.w,
                      q2.x, q2.y, q2.z, q2.w, q3.x, q3.y};
    float o[28];
#pragma unroll
    for (int i = 0; i < 14; i++) { o[2 * i] = b2f(w[i] & 0xffff); o[2 * i + 1] = b2f(w[i] >> 16); }

    float acc[16];
#pragma unroll
    for (int i = 0; i < 16; i++) acc[i] = 0.f;

    const uint4* vb = (const uint4*)(valb + ((size_t)(n * 8 + g) << 16));
#pragma unroll
    for (int k = 0; k < 9; k++) {
        float sx = (float)(px + (k % 3) - 1) + o[2 * k];
        float sy = (float)(py + (k / 3) - 1) + o[2 * k + 1];
        float m = o[18 + k];
        float x0f = floorf(sx), y0f = floorf(sy);
        float tx = sx - x0f, ty = sy - y0f;
        int x0 = (int)x0f, y0 = (int)y0f;
#pragma unroll
        for (int dy = 0; dy < 2; dy++) {
            int iy = y0 + dy;
            if (iy < 0 || iy > 63) continue;
            float wy = dy ? ty : 1.f - ty;
#pragma unroll
            for (int dx = 0; dx < 2; dx++) {
                int ix = x0 + dx;
                if (ix < 0 || ix > 63) continue;
                float wgt = m * wy * (dx ? tx : 1.f - tx);
                const uint4* vp = vb + ((size_t)(iy * 64 + ix)) * 2;
                uint4 v0 = vp[0], v1 = vp[1];
                acc[0]  += wgt * b2f(v0.x & 0xffff); acc[1]  += wgt * b2f(v0.x >> 16);
                acc[2]  += wgt * b2f(v0.y & 0xffff); acc[3]  += wgt * b2f(v0.y >> 16);
                acc[4]  += wgt * b2f(v0.z & 0xffff); acc[5]  += wgt * b2f(v0.z >> 16);
                acc[6]  += wgt * b2f(v0.w & 0xffff); acc[7]  += wgt * b2f(v0.w >> 16);
                acc[8]  += wgt * b2f(v1.x & 0xffff); acc[9]  += wgt * b2f(v1.x >> 16);
                acc[10] += wgt * b2f(v1.y & 0xffff); acc[11] += wgt * b2f(v1.y >> 16);
                acc[12] += wgt * b2f(v1.z & 0xffff); acc[13] += wgt * b2f(v1.z >> 16);
                acc[14] += wgt * b2f(v1.w & 0xffff); acc[15] += wgt * b2f(v1.w >> 16);
            }
        }
    }
    uint32_t u[8];
#pragma unroll
    for (int i = 0; i < 8; i++)
        u[i] = (uint32_t)f2b(acc[2 * i]) | ((uint32_t)f2b(acc[2 * i + 1]) << 16);
    uint4* outp = (uint4*)(accb + ((size_t)(n * 4096 + p)) * 128 + g * 16);
    outp[0] = make_uint4(u[0], u[1], u[2], u[3]);
    outp[1] = make_uint4(u[4], u[5], u[6], u[7]);
}

// ---------------------------------------------------------------------------
// gemm3: D[m=pixel][n=out-ch] = acc x w_out, + b_out, BN, SiLU -> out NCHW fp32
// ---------------------------------------------------------------------------
__launch_bounds__(256)
__global__ void gemm3_kernel(const uint16_t* __restrict__ accb, const uint16_t* __restrict__ wT,
                             const float* __restrict__ b_out, const float* __restrict__ bnc,
                             float* __restrict__ out) {
    __shared__ __align__(16) uint16_t ldsA[128 * 136];
    __shared__ __align__(16) uint16_t ldsW[64 * 136];
    int ct = blockIdx.x;            // 0..1
    int pt = blockIdx.y;            // 0..127
    int p0 = pt * 128, cbase = ct * 64;
    int tid = threadIdx.x;
    int col16 = tid & 15, rowq = tid >> 4;

    const uint4* ag = (const uint4*)accb;
    uint4* la = (uint4*)ldsA;
#pragma unroll
    for (int i = 0; i < 8; i++) {
        int row = i * 16 + rowq;
        la[row * 17 + col16] = ag[(size_t)(p0 + row) * 16 + col16];
    }
    const uint4* wg = (const uint4*)wT;
    uint4* lw = (uint4*)ldsW;
#pragma unroll
    for (int i = 0; i < 4; i++) {
        int row = i * 16 + rowq;
        lw[row * 17 + col16] = wg[(size_t)(384 + cbase + row) * 16 + col16];
    }
    __syncthreads();

    int wv = tid >> 6, lane = tid & 63;
    int ln = lane & 15, quad = lane >> 4;
    f32x4 acc[2][4];
#pragma unroll
    for (int ni = 0; ni < 4; ni++) {
        float b = b_out[cbase + ni * 16 + ln];
        acc[0][ni] = f32x4{b, b, b, b};
        acc[1][ni] = f32x4{b, b, b, b};
    }
#pragma unroll
    for (int kk = 0; kk < 4; kk++) {
        v8bf a0 = *(const v8bf*)&ldsA[((wv * 2 + 0) * 16 + ln) * 136 + kk * 32 + quad * 8];
        v8bf a1 = *(const v8bf*)&ldsA[((wv * 2 + 1) * 16 + ln) * 136 + kk * 32 + quad * 8];
#pragma unroll
        for (int ni = 0; ni < 4; ni++) {
            v8bf b = *(const v8bf*)&ldsW[(ni * 16 + ln) * 136 + kk * 32 + quad * 8];
            acc[0][ni] = __builtin_amdgcn_mfma_f32_16x16x32_bf16(a0, b, acc[0][ni], 0, 0, 0);
            acc[1][ni] = __builtin_amdgcn_mfma_f32_16x16x32_bf16(a1, b, acc[1][ni], 0, 0, 0);
        }
    }
    int nimg = p0 >> 12, pin0 = p0 & 4095;
#pragma unroll
    for (int mi = 0; mi < 2; mi++) {
        int p = pin0 + (wv * 2 + mi) * 16 + quad * 4;
#pragma unroll
        for (int ni = 0; ni < 4; ni++) {
            int cc = cbase + ni * 16 + ln;
            float inv = bnc[cc], add = bnc[128 + cc];
            float4 r;
            float* rp = &r.x;
#pragma unroll
            for (int q = 0; q < 4; q++) {
                float z = acc[mi][ni][q] * inv + add;
                rp[q] = z / (1.f + __expf(-z));
            }
            *(float4*)&out[((size_t)(nimg * 128 + cc) << 12) + p] = r;
        }
    }
}

// ---------------------------------------------------------------------------
extern "C" void kernel_launch(void* const* d_in, const int* in_sizes, int n_in,
                              void* d_out, int out_size, void* d_ws, size_t ws_size,
                              hipStream_t stream) {
    const float* x       = (const float*)d_in[0];
    const float* w_value = (const float*)d_in[1];
    const float* b_value = (const float*)d_in[2];
    const float* w_off   = (const float*)d_in[3];
    const float* b_off   = (const float*)d_in[4];
    const float* w_out   = (const float*)d_in[5];
    const float* b_out   = (const float*)d_in[6];
    const float* gamma   = (const float*)d_in[7];
    const float* beta    = (const float*)d_in[8];
    const float* mean    = (const float*)d_in[9];
    const float* var     = (const float*)d_in[10];
    float* out = (float*)d_out;

    char* ws = (char*)d_ws;
    uint16_t* xf   = (uint16_t*)(ws);                        // 4 MiB
    uint16_t* accb = (uint16_t*)(ws + ((size_t)4 << 20));    // 4 MiB
    uint16_t* valb = (uint16_t*)(ws + ((size_t)8 << 20));    // 4 MiB
    uint16_t* omb  = (uint16_t*)(ws + ((size_t)12 << 20));   // 8 MiB
    uint16_t* wT   = (uint16_t*)(ws + ((size_t)20 << 20));   // 128 KiB
    float*    bnc  = (float*)(ws + ((size_t)20 << 20) + (1 << 18)); // 1 KiB

    hipLaunchKernelGGL(prep_kernel, dim3(256), dim3(256), 0, stream,
                       w_value, w_off, w_out, gamma, beta, mean, var, wT, bnc);
    hipLaunchKernelGGL(transpose_kernel, dim3(512), dim3(256), 0, stream, x, xf);
    hipLaunchKernelGGL(gemm1_kernel, dim3(6, 128), dim3(256), 0, stream,
                       xf, wT, b_value, b_off, valb, omb);
    hipLaunchKernelGGL(gather_kernel, dim3(512), dim3(256), 0, stream, omb, valb, accb);
    hipLaunchKernelGGL(gemm3_kernel, dim3(2, 128), dim3(256), 0, stream,
                       accb, wT, b_out, bnc, out);
}